// Round 3
// baseline (503.602 us; speedup 1.0000x reference)
//
#include <hip/hip_runtime.h>

// Problem constants (fixed by setup_inputs): B=64, H=W=1024, p=64.
#define BATCH   64
#define HEIGHT  1024
#define WIDTH   1024
#define PSZ     64
#define NPH     16              // HEIGHT / PSZ
#define NPW     16              // WIDTH / PSZ
#define HALFROWS 32             // rows per block (half a strip)

#define ABS4(a,b) (fabsf((a).x-(b).x)+fabsf((a).y-(b).y)+fabsf((a).z-(b).z)+fabsf((a).w-(b).w))

// Kernel 1: 2048 blocks x 256 threads. Block = (image, patch-row, half-strip):
// 32 contiguous rows of 4 KB each from both inputs, fully coalesced.
// Explicit 8-wide load batches (8 float4 temps) force >=8 loads in flight per
// wave; 4 independent accumulators. Width-16 shuffle reduce -> 16 partial
// patch sums per block, stored straight to ws (no LDS, no syncthreads).
__global__ __launch_bounds__(256) void patch_halfstrip_kernel(
    const float* __restrict__ out_p, const float* __restrict__ tgt_p,
    float* __restrict__ part)
{
    const int blk  = blockIdx.x;          // [0, BATCH*NPH*2)
    const int img  = blk >> 5;
    const int prow = (blk >> 1) & 15;
    const int half = blk & 1;

    const size_t base_f4 = (size_t)img * (HEIGHT * WIDTH / 4)
                         + (size_t)(prow * PSZ + half * HALFROWS) * (WIDTH / 4)
                         + threadIdx.x;
    const float4* __restrict__ po = reinterpret_cast<const float4*>(out_p) + base_f4;
    const float4* __restrict__ pt = reinterpret_cast<const float4*>(tgt_p) + base_f4;

    float s0 = 0.f, s1 = 0.f, s2 = 0.f, s3 = 0.f;
#pragma unroll
    for (int r = 0; r < HALFROWS; r += 4) {
        const float4 a0 = po[(size_t)(r + 0) * 256];
        const float4 a1 = po[(size_t)(r + 1) * 256];
        const float4 a2 = po[(size_t)(r + 2) * 256];
        const float4 a3 = po[(size_t)(r + 3) * 256];
        const float4 b0 = pt[(size_t)(r + 0) * 256];
        const float4 b1 = pt[(size_t)(r + 1) * 256];
        const float4 b2 = pt[(size_t)(r + 2) * 256];
        const float4 b3 = pt[(size_t)(r + 3) * 256];
        s0 += ABS4(a0, b0);
        s1 += ABS4(a1, b1);
        s2 += ABS4(a2, b2);
        s3 += ABS4(a3, b3);
    }
    float s = (s0 + s1) + (s2 + s3);

    // width-16 segment reduce: leader of each 16-lane group holds the partial
    // patch sum (patch index = tid>>4) for this half-strip.
#pragma unroll
    for (int off = 8; off > 0; off >>= 1)
        s += __shfl_down(s, off, 16);

    if ((threadIdx.x & 15) == 0)
        part[blk * NPW + (threadIdx.x >> 4)] = s;
}

// Kernel 2: one block per image. part layout: [img][prow][half][patch]
// = img*512 + prow*32 + half*16 + p. Thread t owns patch (prow=t>>4, p=t&15):
// sum the two half-strip partials, scale to mean, block-max -> img_max[img].
__global__ __launch_bounds__(256) void image_max_kernel(
    const float* __restrict__ part, float* __restrict__ img_max)
{
    const int img = blockIdx.x;
    const int t   = threadIdx.x;
    const int idx = img * 512 + (t >> 4) * 32 + (t & 15);
    float ps = (part[idx] + part[idx + 16]) * (1.0f / (PSZ * PSZ));

#pragma unroll
    for (int off = 32; off > 0; off >>= 1)
        ps = fmaxf(ps, __shfl_down(ps, off, 64));

    __shared__ float lds[4];
    if ((t & 63) == 0) lds[t >> 6] = ps;
    __syncthreads();
    if (t == 0)
        img_max[img] = fmaxf(fmaxf(lds[0], lds[1]), fmaxf(lds[2], lds[3]));
}

// Kernel 3: single wave, mean over 64 image maxes.
__global__ __launch_bounds__(64) void mean_kernel(
    const float* __restrict__ img_max, float* __restrict__ result)
{
    float v = img_max[threadIdx.x];
#pragma unroll
    for (int off = 32; off > 0; off >>= 1)
        v += __shfl_down(v, off, 64);
    if (threadIdx.x == 0) result[0] = v * (1.0f / BATCH);
}

extern "C" void kernel_launch(void* const* d_in, const int* in_sizes, int n_in,
                              void* d_out, int out_size, void* d_ws, size_t ws_size,
                              hipStream_t stream) {
    const float* out_p = (const float*)d_in[0];
    const float* tgt_p = (const float*)d_in[1];
    // d_in[2] is patch_size (=64), baked into kernel constants.
    float* part    = (float*)d_ws;                   // 2048*16 floats = 128 KB
    float* img_max = part + BATCH * NPH * 2 * NPW;   // 64 floats
    float* result  = (float*)d_out;

    patch_halfstrip_kernel<<<BATCH * NPH * 2, 256, 0, stream>>>(out_p, tgt_p, part);
    image_max_kernel<<<BATCH, 256, 0, stream>>>(part, img_max);
    mean_kernel<<<1, 64, 0, stream>>>(img_max, result);
}